// Round 1
// baseline (468.139 us; speedup 1.0000x reference)
//
#include <hip/hip_runtime.h>
#include <math.h>

#define F_DIM 32
#define A_DIM 8
#define T_DIM 400

static __device__ __forceinline__ float az_step()     { return 0.78539816339744830962f; } // pi/4
static __device__ __forceinline__ float pi_f()        { return 3.14159265358979323846f; }
static __device__ __forceinline__ float inv_sin_om()  { return 1.41421356237309504880f; } // 1/sin(pi/4)
static __device__ __forceinline__ float four_ov_pi()  { return 1.27323954473516268615f; }

// ---------------- transpose (F, A*T*T) -> (A*T*T, F) ----------------
__global__ __launch_bounds__(256) void transpose_kernel(const float* __restrict__ src,
                                                        float* __restrict__ dst, int M) {
    __shared__ float t[32][33];
    const int m0 = blockIdx.x * 32;
    const int tx = threadIdx.x & 31;
    const int ty = threadIdx.x >> 5; // 0..7
#pragma unroll
    for (int i = 0; i < 4; ++i) {
        int f = ty + 8 * i;
        t[f][tx] = src[(size_t)f * M + (m0 + tx)];
    }
    __syncthreads();
#pragma unroll
    for (int i = 0; i < 4; ++i) {
        int m = ty + 8 * i;
        dst[(size_t)(m0 + m) * F_DIM + tx] = t[tx][m];
    }
}

// ---------------- per-point parameter math (matches torch.bucketize / ref) ----------------
struct PtParams {
    int   base[4];   // (a_l,il0) (a_l,ir0) (a_r,il0) (a_r,ir0), element index incl. *F
    int   d1;        // (ir1-il1)*F  (0 or F)
    float wA[4];     // {w1*ul, w1*ur, w2*ul, w2*ur}
    float vl, vr;
};

static __device__ __forceinline__ PtParams compute_params(float x, float y, float d) {
    PtParams P;
    // axis 0
    int ir0 = (int)ceilf(x * 4.0f); if (ir0 > T_DIM - 1) ir0 = T_DIM - 1; if (ir0 < 0) ir0 = 0;
    int il0 = ir0 - 1; if (il0 < 0) il0 = 0;
    float dl0 = fmaxf(x - (float)il0 * 0.25f, 0.0f);
    float dr0 = fmaxf((float)ir0 * 0.25f - x, 0.0f);
    if (dl0 == 0.0f && dr0 == 0.0f) { dl0 = 1.0f; dr0 = 1.0f; }
    float inv0 = 1.0f / (dl0 + dr0);
    float ul = dr0 * inv0, ur = dl0 * inv0;
    // axis 1
    int ir1 = (int)ceilf(y * 4.0f); if (ir1 > T_DIM - 1) ir1 = T_DIM - 1; if (ir1 < 0) ir1 = 0;
    int il1 = ir1 - 1; if (il1 < 0) il1 = 0;
    float dl1 = fmaxf(y - (float)il1 * 0.25f, 0.0f);
    float dr1 = fmaxf((float)ir1 * 0.25f - y, 0.0f);
    if (dl1 == 0.0f && dr1 == 0.0f) { dl1 = 1.0f; dr1 = 1.0f; }
    float inv1 = 1.0f / (dl1 + dr1);
    P.vl = dr1 * inv1; P.vr = dl1 * inv1;
    // azimuth
    int k = (int)floorf((d + pi_f()) * four_ov_pi());
    if (k < 0) k = 0; if (k > A_DIM - 1) k = A_DIM - 1;
    int al = k, ar = (k + 1) & (A_DIM - 1);
    float theta = fmaxf(d - (-pi_f() + (float)k * az_step()), 0.0f);
    float w1 = sinf(az_step() - theta) * inv_sin_om();
    float w2 = sinf(theta) * inv_sin_om();
    P.wA[0] = w1 * ul; P.wA[1] = w1 * ur;
    P.wA[2] = w2 * ul; P.wA[3] = w2 * ur;
    P.base[0] = ((al * T_DIM + il0) * T_DIM + il1) * F_DIM;
    P.base[1] = ((al * T_DIM + ir0) * T_DIM + il1) * F_DIM;
    P.base[2] = ((ar * T_DIM + il0) * T_DIM + il1) * F_DIM;
    P.base[3] = ((ar * T_DIM + ir0) * T_DIM + il1) * F_DIM;
    P.d1 = (ir1 - il1) * F_DIM;
    return P;
}

// ---------------- main gather kernel (transposed table) ----------------
__global__ __launch_bounds__(256) void interp_kernel(const float* __restrict__ pos,
                                                     const float* __restrict__ dirs,
                                                     const float* __restrict__ Gt,
                                                     float* __restrict__ out, int N) {
    __shared__ int   s_base[64][4];
    __shared__ int   s_d1[64];
    __shared__ float s_wA[64][4];
    __shared__ float s_vl[64];
    __shared__ float s_vr[64];
    __shared__ float s_tile[64][33];

    const int n0 = blockIdx.x * 64;
    const int t = threadIdx.x;

    if (t < 64) {
        int n = n0 + t;
        float x = 0.0f, y = 0.0f, d = 0.0f;
        if (n < N) {
            float2 p = ((const float2*)pos)[n];
            x = p.x; y = p.y;
            d = dirs[n];
        }
        PtParams P = compute_params(x, y, d);
#pragma unroll
        for (int j = 0; j < 4; ++j) { s_base[t][j] = P.base[j]; s_wA[t][j] = P.wA[j]; }
        s_d1[t] = P.d1;
        s_vl[t] = P.vl; s_vr[t] = P.vr;
    }
    __syncthreads();

    const int g = t >> 5;   // 32-lane group id, 0..7
    const int l = t & 31;   // feature id
#pragma unroll
    for (int it = 0; it < 8; ++it) {
        int p = g * 8 + it;
        float vl = s_vl[p], vr = s_vr[p];
        int d1 = s_d1[p];
        float acc = 0.0f;
#pragma unroll
        for (int j = 0; j < 4; ++j) {
            const float* gp = Gt + s_base[p][j] + l;
            float w = s_wA[p][j];
            acc = fmaf(w * vl, gp[0],  acc);
            acc = fmaf(w * vr, gp[d1], acc);
        }
        s_tile[p][l] = acc;
    }
    __syncthreads();

    const int j = t & 63;
    const int f0 = t >> 6; // 0..3
    int n = n0 + j;
    if (n < N) {
#pragma unroll
        for (int i = 0; i < 8; ++i) {
            int f = f0 * 8 + i;
            out[(size_t)f * N + n] = s_tile[j][f];
        }
    }
}

// ---------------- fallback: direct gather from original layout ----------------
__global__ __launch_bounds__(256) void direct_kernel(const float* __restrict__ pos,
                                                     const float* __restrict__ dirs,
                                                     const float* __restrict__ grid,
                                                     float* __restrict__ out, int N) {
    int n = blockIdx.x * blockDim.x + threadIdx.x;
    if (n >= N) return;
    float2 p = ((const float2*)pos)[n];
    PtParams P = compute_params(p.x, p.y, dirs[n]);
    // convert f-innermost bases to original-layout bases (divide out *F)
    int b[4], d1 = P.d1 / F_DIM;
#pragma unroll
    for (int j = 0; j < 4; ++j) b[j] = P.base[j] / F_DIM;
    const int fstride = A_DIM * T_DIM * T_DIM;
    for (int f = 0; f < F_DIM; ++f) {
        const float* gf = grid + (size_t)f * fstride;
        float acc = 0.0f;
#pragma unroll
        for (int j = 0; j < 4; ++j) {
            float w = P.wA[j];
            acc = fmaf(w * P.vl, gf[b[j]],      acc);
            acc = fmaf(w * P.vr, gf[b[j] + d1], acc);
        }
        out[(size_t)f * N + n] = acc;
    }
}

extern "C" void kernel_launch(void* const* d_in, const int* in_sizes, int n_in,
                              void* d_out, int out_size, void* d_ws, size_t ws_size,
                              hipStream_t stream) {
    const float* pos  = (const float*)d_in[0];
    const float* dirs = (const float*)d_in[1];
    const float* grid = (const float*)d_in[2];
    float* out = (float*)d_out;
    const int N = in_sizes[1];

    const size_t needed = (size_t)A_DIM * T_DIM * T_DIM * F_DIM * sizeof(float);
    if (ws_size >= needed) {
        float* Gt = (float*)d_ws;
        const int M = A_DIM * T_DIM * T_DIM;
        transpose_kernel<<<M / 32, 256, 0, stream>>>(grid, Gt, M);
        interp_kernel<<<(N + 63) / 64, 256, 0, stream>>>(pos, dirs, Gt, out, N);
    } else {
        direct_kernel<<<(N + 255) / 256, 256, 0, stream>>>(pos, dirs, grid, out, N);
    }
}

// Round 2
// 393.300 us; speedup vs baseline: 1.1903x; 1.1903x over previous
//
#include <hip/hip_runtime.h>
#include <math.h>

#define F_DIM 32
#define A_DIM 8
#define T_DIM 400

static __device__ __forceinline__ float az_step()     { return 0.78539816339744830962f; } // pi/4
static __device__ __forceinline__ float pi_f()        { return 3.14159265358979323846f; }
static __device__ __forceinline__ float inv_sin_om()  { return 1.41421356237309504880f; } // 1/sin(pi/4)
static __device__ __forceinline__ float four_ov_pi()  { return 1.27323954473516268615f; }

static __device__ __forceinline__ float b2f(unsigned short u) {
    unsigned int x = ((unsigned int)u) << 16;
    return __uint_as_float(x);
}
static __device__ __forceinline__ unsigned short f2b(float f) {
    unsigned int x = __float_as_uint(f);
    unsigned int r = (x + 0x7FFFu + ((x >> 16) & 1u)) >> 16; // round-to-nearest-even
    return (unsigned short)r;
}

// ---------------- transpose+quantize (F, M) f32 -> (M, F) bf16 ----------------
// m-tile = 256 per block: 1 KB sequential per f-row per block (DRAM page locality),
// float4 loads, LDS staging, ushort4 coalesced stores.
__global__ __launch_bounds__(256) void transpose_bf16_kernel(const float* __restrict__ src,
                                                             unsigned short* __restrict__ dst,
                                                             int M) {
    __shared__ float t[F_DIM][257]; // stride 257: bank = (f+m)&31, ~2-way max (free)
    const int m0 = blockIdx.x * 256;
    const int f  = threadIdx.x >> 3;        // 0..31
    const int ms = (threadIdx.x & 7) * 4;   // 0,4,...,28
#pragma unroll
    for (int it = 0; it < 8; ++it) {
        int m = ms + 32 * it;
        float4 v = *(const float4*)(src + (size_t)f * M + m0 + m);
        t[f][m] = v.x; t[f][m + 1] = v.y; t[f][m + 2] = v.z; t[f][m + 3] = v.w;
    }
    __syncthreads();
    const int fi = (threadIdx.x & 7) * 4;   // 0,4,...,28
    const int mb = threadIdx.x >> 3;        // 0..31
#pragma unroll
    for (int it = 0; it < 8; ++it) {
        int m = mb + 32 * it;
        ushort4 o;
        o.x = f2b(t[fi][m]);
        o.y = f2b(t[fi + 1][m]);
        o.z = f2b(t[fi + 2][m]);
        o.w = f2b(t[fi + 3][m]);
        *(ushort4*)(dst + (size_t)(m0 + m) * F_DIM + fi) = o;
    }
}

// ---------------- per-point parameter math (matches torch.bucketize / ref) ----------------
struct PtParams {
    int   base[4];   // (a_l,il0) (a_l,ir0) (a_r,il0) (a_r,ir0), element index incl. *F
    int   d1;        // (ir1-il1)*F  (0 or F)
    float wA[4];     // {w1*ul, w1*ur, w2*ul, w2*ur}
    float vl, vr;
};

static __device__ __forceinline__ PtParams compute_params(float x, float y, float d) {
    PtParams P;
    // axis 0
    int ir0 = (int)ceilf(x * 4.0f); if (ir0 > T_DIM - 1) ir0 = T_DIM - 1; if (ir0 < 0) ir0 = 0;
    int il0 = ir0 - 1; if (il0 < 0) il0 = 0;
    float dl0 = fmaxf(x - (float)il0 * 0.25f, 0.0f);
    float dr0 = fmaxf((float)ir0 * 0.25f - x, 0.0f);
    if (dl0 == 0.0f && dr0 == 0.0f) { dl0 = 1.0f; dr0 = 1.0f; }
    float inv0 = 1.0f / (dl0 + dr0);
    float ul = dr0 * inv0, ur = dl0 * inv0;
    // axis 1
    int ir1 = (int)ceilf(y * 4.0f); if (ir1 > T_DIM - 1) ir1 = T_DIM - 1; if (ir1 < 0) ir1 = 0;
    int il1 = ir1 - 1; if (il1 < 0) il1 = 0;
    float dl1 = fmaxf(y - (float)il1 * 0.25f, 0.0f);
    float dr1 = fmaxf((float)ir1 * 0.25f - y, 0.0f);
    if (dl1 == 0.0f && dr1 == 0.0f) { dl1 = 1.0f; dr1 = 1.0f; }
    float inv1 = 1.0f / (dl1 + dr1);
    P.vl = dr1 * inv1; P.vr = dl1 * inv1;
    // azimuth
    int k = (int)floorf((d + pi_f()) * four_ov_pi());
    if (k < 0) k = 0; if (k > A_DIM - 1) k = A_DIM - 1;
    int al = k, ar = (k + 1) & (A_DIM - 1);
    float theta = fmaxf(d - (-pi_f() + (float)k * az_step()), 0.0f);
    float w1 = sinf(az_step() - theta) * inv_sin_om();
    float w2 = sinf(theta) * inv_sin_om();
    P.wA[0] = w1 * ul; P.wA[1] = w1 * ur;
    P.wA[2] = w2 * ul; P.wA[3] = w2 * ur;
    P.base[0] = ((al * T_DIM + il0) * T_DIM + il1) * F_DIM;
    P.base[1] = ((al * T_DIM + ir0) * T_DIM + il1) * F_DIM;
    P.base[2] = ((ar * T_DIM + il0) * T_DIM + il1) * F_DIM;
    P.base[3] = ((ar * T_DIM + ir0) * T_DIM + il1) * F_DIM;
    P.d1 = (ir1 - il1) * F_DIM;
    return P;
}

// ---------------- main gather kernel (transposed bf16 table) ----------------
__global__ __launch_bounds__(256) void interp_kernel(const float* __restrict__ pos,
                                                     const float* __restrict__ dirs,
                                                     const unsigned short* __restrict__ Gt,
                                                     float* __restrict__ out, int N) {
    __shared__ int   s_base[64][4];
    __shared__ int   s_d1[64];
    __shared__ float s_wA[64][4];
    __shared__ float s_vl[64];
    __shared__ float s_vr[64];
    __shared__ float s_tile[64][33];

    const int n0 = blockIdx.x * 64;
    const int t = threadIdx.x;

    if (t < 64) {
        int n = n0 + t;
        float x = 0.0f, y = 0.0f, d = 0.0f;
        if (n < N) {
            float2 p = ((const float2*)pos)[n];
            x = p.x; y = p.y;
            d = dirs[n];
        }
        PtParams P = compute_params(x, y, d);
#pragma unroll
        for (int j = 0; j < 4; ++j) { s_base[t][j] = P.base[j]; s_wA[t][j] = P.wA[j]; }
        s_d1[t] = P.d1;
        s_vl[t] = P.vl; s_vr[t] = P.vr;
    }
    __syncthreads();

    const int g = t >> 5;   // 32-lane group id, 0..7
    const int l = t & 31;   // feature id
#pragma unroll
    for (int it = 0; it < 8; ++it) {
        int p = g * 8 + it;
        float vl = s_vl[p], vr = s_vr[p];
        int d1 = s_d1[p];
        float acc = 0.0f;
#pragma unroll
        for (int j = 0; j < 4; ++j) {
            const unsigned short* gp = Gt + s_base[p][j] + l;
            float w = s_wA[p][j];
            acc = fmaf(w * vl, b2f(gp[0]),  acc);
            acc = fmaf(w * vr, b2f(gp[d1]), acc);
        }
        s_tile[p][l] = acc;
    }
    __syncthreads();

    const int j = t & 63;
    const int f0 = t >> 6; // 0..3
    int n = n0 + j;
    if (n < N) {
#pragma unroll
        for (int i = 0; i < 8; ++i) {
            int f = f0 * 8 + i;
            out[(size_t)f * N + n] = s_tile[j][f];
        }
    }
}

// ---------------- fallback: direct gather from original layout ----------------
__global__ __launch_bounds__(256) void direct_kernel(const float* __restrict__ pos,
                                                     const float* __restrict__ dirs,
                                                     const float* __restrict__ grid,
                                                     float* __restrict__ out, int N) {
    int n = blockIdx.x * blockDim.x + threadIdx.x;
    if (n >= N) return;
    float2 p = ((const float2*)pos)[n];
    PtParams P = compute_params(p.x, p.y, dirs[n]);
    int b[4], d1 = P.d1 / F_DIM;
#pragma unroll
    for (int j = 0; j < 4; ++j) b[j] = P.base[j] / F_DIM;
    const int fstride = A_DIM * T_DIM * T_DIM;
    for (int f = 0; f < F_DIM; ++f) {
        const float* gf = grid + (size_t)f * fstride;
        float acc = 0.0f;
#pragma unroll
        for (int j = 0; j < 4; ++j) {
            float w = P.wA[j];
            acc = fmaf(w * P.vl, gf[b[j]],      acc);
            acc = fmaf(w * P.vr, gf[b[j] + d1], acc);
        }
        out[(size_t)f * N + n] = acc;
    }
}

extern "C" void kernel_launch(void* const* d_in, const int* in_sizes, int n_in,
                              void* d_out, int out_size, void* d_ws, size_t ws_size,
                              hipStream_t stream) {
    const float* pos  = (const float*)d_in[0];
    const float* dirs = (const float*)d_in[1];
    const float* grid = (const float*)d_in[2];
    float* out = (float*)d_out;
    const int N = in_sizes[1];

    const size_t needed = (size_t)A_DIM * T_DIM * T_DIM * F_DIM * sizeof(unsigned short);
    if (ws_size >= needed) {
        unsigned short* Gt = (unsigned short*)d_ws;
        const int M = A_DIM * T_DIM * T_DIM; // 1,280,000 — divisible by 256
        transpose_bf16_kernel<<<M / 256, 256, 0, stream>>>(grid, Gt, M);
        interp_kernel<<<(N + 63) / 64, 256, 0, stream>>>(pos, dirs, Gt, out, N);
    } else {
        direct_kernel<<<(N + 255) / 256, 256, 0, stream>>>(pos, dirs, grid, out, N);
    }
}